// Round 1
// baseline (340.079 us; speedup 1.0000x reference)
//
#include <hip/hip_runtime.h>

#define N_NODES 50000
#define N_EDGES 800000
#define E_TOT   (N_EDGES + N_NODES)   // 850000 (self-loops appended)
#define D_IN    128
#define D_HID   64

#define SCAN_B        256
#define N_SCAN_BLOCKS ((N_NODES + SCAN_B - 1) / SCAN_B)   // 196

// ---------------- graph build ----------------

__global__ __launch_bounds__(256) void k_count(const int* __restrict__ dst,
                                               unsigned* __restrict__ cnt) {
  int e = blockIdx.x * blockDim.x + threadIdx.x;
  if (e < N_EDGES) atomicAdd(&cnt[dst[e]], 1u);
}

__global__ __launch_bounds__(256) void k_dis(unsigned* __restrict__ cnt,
                                             float* __restrict__ dis) {
  int i = blockIdx.x * blockDim.x + threadIdx.x;
  if (i < N_NODES) {
    unsigned c = cnt[i] + 1u;          // + self-loop
    cnt[i] = c;
    dis[i] = rsqrtf((float)c);
  }
}

__global__ __launch_bounds__(SCAN_B) void k_scan1(const unsigned* __restrict__ cnt,
                                                  unsigned* __restrict__ excl,
                                                  unsigned* __restrict__ bsum) {
  __shared__ unsigned s[SCAN_B];
  int i = blockIdx.x * SCAN_B + threadIdx.x;
  unsigned v = (i < N_NODES) ? cnt[i] : 0u;
  s[threadIdx.x] = v;
  __syncthreads();
  for (int off = 1; off < SCAN_B; off <<= 1) {
    unsigned t = (threadIdx.x >= off) ? s[threadIdx.x - off] : 0u;
    __syncthreads();
    s[threadIdx.x] += t;
    __syncthreads();
  }
  if (i < N_NODES) excl[i] = s[threadIdx.x] - v;
  if (threadIdx.x == SCAN_B - 1) bsum[blockIdx.x] = s[SCAN_B - 1];
}

__global__ __launch_bounds__(SCAN_B) void k_scan2(unsigned* __restrict__ bsum) {
  __shared__ unsigned s[SCAN_B];
  unsigned v = (threadIdx.x < N_SCAN_BLOCKS) ? bsum[threadIdx.x] : 0u;
  s[threadIdx.x] = v;
  __syncthreads();
  for (int off = 1; off < SCAN_B; off <<= 1) {
    unsigned t = (threadIdx.x >= off) ? s[threadIdx.x - off] : 0u;
    __syncthreads();
    s[threadIdx.x] += t;
    __syncthreads();
  }
  if (threadIdx.x < N_SCAN_BLOCKS) bsum[threadIdx.x] = s[threadIdx.x] - v;  // exclusive
}

__global__ __launch_bounds__(256) void k_scan3(unsigned* __restrict__ rowptr,
                                               unsigned* __restrict__ fill,
                                               const unsigned* __restrict__ bsum) {
  int i = blockIdx.x * blockDim.x + threadIdx.x;
  if (i < N_NODES) {
    unsigned r = rowptr[i] + bsum[i / SCAN_B];
    rowptr[i] = r;
    fill[i] = r;
  }
  if (i == 0) rowptr[N_NODES] = E_TOT;
}

__global__ __launch_bounds__(256) void k_fill(const int* __restrict__ esrc_in,
                                              const int* __restrict__ edst_in,
                                              const float* __restrict__ dis,
                                              unsigned* __restrict__ fill,
                                              unsigned* __restrict__ csr_src,
                                              float* __restrict__ csr_nrm) {
  int e = blockIdx.x * blockDim.x + threadIdx.x;
  if (e >= E_TOT) return;
  int s, d;
  if (e < N_EDGES) { s = esrc_in[e]; d = edst_in[e]; }
  else             { s = d = e - N_EDGES; }          // self-loops
  float nrm = dis[s] * dis[d];
  unsigned pos = atomicAdd(&fill[d], 1u);
  csr_src[pos] = (unsigned)s;
  csr_nrm[pos] = nrm;
}

// ---------------- dense transform: Y[N][64] = X[N][DIN] @ W[DIN][64] ----------------

template <int DIN>
__global__ __launch_bounds__(256) void k_gemm(const float* __restrict__ X,
                                              const float* __restrict__ W,
                                              float* __restrict__ Y) {
  // 16 rows / block; thread t: col = t&63, rows ty*4..ty*4+3 (ty = t>>6)
  __shared__ float sW[DIN * 64];     // [k][col]
  __shared__ float sXT[DIN][20];     // transposed, padded (+4) to dodge bank conflicts
  const int tid  = threadIdx.x;
  const int col  = tid & 63;
  const int ty   = tid >> 6;         // 0..3
  const int row0 = blockIdx.x * 16;

  for (int i = tid; i < DIN * 64; i += 256) sW[i] = W[i];
  for (int i = tid; i < 16 * DIN; i += 256) {
    int lr = i / DIN, k = i % DIN;
    int r = row0 + lr;
    sXT[k][lr] = (r < N_NODES) ? X[(size_t)r * DIN + k] : 0.f;
  }
  __syncthreads();

  float4 acc = {0.f, 0.f, 0.f, 0.f};
#pragma unroll 4
  for (int k = 0; k < DIN; k++) {
    float w = sW[k * 64 + col];                                  // 2-way (free)
    float4 xv = *reinterpret_cast<const float4*>(&sXT[k][ty * 4]);  // broadcast in-wave
    acc.x += xv.x * w; acc.y += xv.y * w; acc.z += xv.z * w; acc.w += xv.w * w;
  }
#pragma unroll
  for (int r = 0; r < 4; r++) {
    int row = row0 + ty * 4 + r;
    if (row < N_NODES) Y[(size_t)row * 64 + col] = (&acc.x)[r];
  }
}

// ---------------- aggregate: OUT[i][:] = relu?( sum_e nrm*XW[src][:] + b ) ----------------

template <bool RELU>
__global__ __launch_bounds__(256) void k_agg(const float* __restrict__ XW,
                                             const unsigned* __restrict__ rowptr,
                                             const unsigned* __restrict__ csr_src,
                                             const float* __restrict__ csr_nrm,
                                             const float* __restrict__ bias,
                                             float* __restrict__ OUT) {
  int wave = (int)((blockIdx.x * blockDim.x + threadIdx.x) >> 6);
  int lane = threadIdx.x & 63;
  if (wave >= N_NODES) return;
  unsigned beg = rowptr[wave], end = rowptr[wave + 1];
  float acc = 0.f;
  for (unsigned j = beg; j < end; j += 64) {
    int nj = (int)min(64u, end - j);
    unsigned s = 0u; float nrm = 0.f;
    if (j + lane < end) { s = csr_src[j + lane]; nrm = csr_nrm[j + lane]; }
    for (int k = 0; k < nj; k++) {
      unsigned sk = (unsigned)__shfl((int)s, k);
      float    nk = __shfl(nrm, k);
      acc += nk * XW[(size_t)sk * 64 + lane];   // 256B coalesced row gather
    }
  }
  acc += bias[lane];
  if (RELU) acc = fmaxf(acc, 0.f);
  OUT[(size_t)wave * 64 + lane] = acc;
}

// ---------------- launch ----------------

extern "C" void kernel_launch(void* const* d_in, const int* in_sizes, int n_in,
                              void* d_out, int out_size, void* d_ws, size_t ws_size,
                              hipStream_t stream) {
  const float* x    = (const float*)d_in[0];
  const int*   eidx = (const int*)d_in[1];      // [2][800000], int32
  const float* W1   = (const float*)d_in[2];
  const float* b1   = (const float*)d_in[3];
  const float* W2   = (const float*)d_in[4];
  const float* b2   = (const float*)d_in[5];
  const float* W3   = (const float*)d_in[6];
  const float* b3   = (const float*)d_in[7];
  float* out = (float*)d_out;

  const int* e_src = eidx;
  const int* e_dst = eidx + N_EDGES;

  size_t off = 0;
  auto alloc = [&](size_t bytes) -> void* {
    void* p = (char*)d_ws + off;
    off += (bytes + 255) & ~(size_t)255;
    return p;
  };
  unsigned* cnt     = (unsigned*)alloc((size_t)N_NODES * 4);
  unsigned* rowptr  = (unsigned*)alloc((size_t)(N_NODES + 1) * 4);
  unsigned* fill    = (unsigned*)alloc((size_t)N_NODES * 4);
  unsigned* bsum    = (unsigned*)alloc((size_t)SCAN_B * 4);
  float*    dis     = (float*)alloc((size_t)N_NODES * 4);
  unsigned* csr_src = (unsigned*)alloc((size_t)E_TOT * 4);
  float*    csr_nrm = (float*)alloc((size_t)E_TOT * 4);
  float*    xw      = (float*)alloc((size_t)N_NODES * 64 * 4);
  float*    h       = (float*)alloc((size_t)N_NODES * 64 * 4);

  // ---- build graph structure (per call; deterministic work) ----
  hipMemsetAsync(cnt, 0, (size_t)N_NODES * 4, stream);
  k_count<<<(N_EDGES + 255) / 256, 256, 0, stream>>>(e_dst, cnt);
  k_dis<<<(N_NODES + 255) / 256, 256, 0, stream>>>(cnt, dis);
  k_scan1<<<N_SCAN_BLOCKS, SCAN_B, 0, stream>>>(cnt, rowptr, bsum);
  k_scan2<<<1, SCAN_B, 0, stream>>>(bsum);
  k_scan3<<<(N_NODES + 255) / 256, 256, 0, stream>>>(rowptr, fill, bsum);
  k_fill<<<(E_TOT + 255) / 256, 256, 0, stream>>>(e_src, e_dst, dis, fill, csr_src, csr_nrm);

  const int gemm_grid = (N_NODES + 15) / 16;          // 3125
  const int agg_grid  = (N_NODES * 64 + 255) / 256;   // 12500

  // ---- layer 1: 128 -> 64, relu ----
  k_gemm<D_IN><<<gemm_grid, 256, 0, stream>>>(x, W1, xw);
  k_agg<true><<<agg_grid, 256, 0, stream>>>(xw, rowptr, csr_src, csr_nrm, b1, h);
  // ---- layer 2: 64 -> 64, relu ----
  k_gemm<D_HID><<<gemm_grid, 256, 0, stream>>>(h, W2, xw);
  k_agg<true><<<agg_grid, 256, 0, stream>>>(xw, rowptr, csr_src, csr_nrm, b2, h);
  // ---- layer 3: 64 -> 64, no activation ----
  k_gemm<D_HID><<<gemm_grid, 256, 0, stream>>>(h, W3, xw);
  k_agg<false><<<agg_grid, 256, 0, stream>>>(xw, rowptr, csr_src, csr_nrm, b3, out);
}

// Round 2
// 257.263 us; speedup vs baseline: 1.3219x; 1.3219x over previous
//
#include <hip/hip_runtime.h>

#define N_NODES 50000
#define N_EDGES 800000
#define E_TOT   (N_EDGES + N_NODES)   // 850000 (self-loops appended)
#define D_IN    128
#define D_HID   64

#define SCAN_B        256
#define N_SCAN_BLOCKS ((N_NODES + SCAN_B - 1) / SCAN_B)   // 196

// ---------------- graph build ----------------

__global__ __launch_bounds__(256) void k_count(const int* __restrict__ dst,
                                               unsigned* __restrict__ cnt) {
  int e = blockIdx.x * blockDim.x + threadIdx.x;
  if (e < N_EDGES) atomicAdd(&cnt[dst[e]], 1u);
}

__global__ __launch_bounds__(256) void k_dis(unsigned* __restrict__ cnt,
                                             float* __restrict__ dis) {
  int i = blockIdx.x * blockDim.x + threadIdx.x;
  if (i < N_NODES) {
    unsigned c = cnt[i] + 1u;          // + self-loop
    cnt[i] = c;
    dis[i] = rsqrtf((float)c);
  }
}

__global__ __launch_bounds__(SCAN_B) void k_scan1(const unsigned* __restrict__ cnt,
                                                  unsigned* __restrict__ excl,
                                                  unsigned* __restrict__ bsum) {
  __shared__ unsigned s[SCAN_B];
  int i = blockIdx.x * SCAN_B + threadIdx.x;
  unsigned v = (i < N_NODES) ? cnt[i] : 0u;
  s[threadIdx.x] = v;
  __syncthreads();
  for (int off = 1; off < SCAN_B; off <<= 1) {
    unsigned t = (threadIdx.x >= off) ? s[threadIdx.x - off] : 0u;
    __syncthreads();
    s[threadIdx.x] += t;
    __syncthreads();
  }
  if (i < N_NODES) excl[i] = s[threadIdx.x] - v;
  if (threadIdx.x == SCAN_B - 1) bsum[blockIdx.x] = s[SCAN_B - 1];
}

__global__ __launch_bounds__(SCAN_B) void k_scan2(unsigned* __restrict__ bsum) {
  __shared__ unsigned s[SCAN_B];
  unsigned v = (threadIdx.x < N_SCAN_BLOCKS) ? bsum[threadIdx.x] : 0u;
  s[threadIdx.x] = v;
  __syncthreads();
  for (int off = 1; off < SCAN_B; off <<= 1) {
    unsigned t = (threadIdx.x >= off) ? s[threadIdx.x - off] : 0u;
    __syncthreads();
    s[threadIdx.x] += t;
    __syncthreads();
  }
  if (threadIdx.x < N_SCAN_BLOCKS) bsum[threadIdx.x] = s[threadIdx.x] - v;  // exclusive
}

__global__ __launch_bounds__(256) void k_scan3(unsigned* __restrict__ rowptr,
                                               unsigned* __restrict__ fill,
                                               const unsigned* __restrict__ bsum) {
  int i = blockIdx.x * blockDim.x + threadIdx.x;
  if (i < N_NODES) {
    unsigned r = rowptr[i] + bsum[i / SCAN_B];
    rowptr[i] = r;
    fill[i] = r;
  }
  if (i == 0) rowptr[N_NODES] = E_TOT;
}

__global__ __launch_bounds__(256) void k_fill(const int* __restrict__ esrc_in,
                                              const int* __restrict__ edst_in,
                                              const float* __restrict__ dis,
                                              unsigned* __restrict__ fill,
                                              uint2* __restrict__ csr) {
  int e = blockIdx.x * blockDim.x + threadIdx.x;
  if (e >= E_TOT) return;
  int s, d;
  if (e < N_EDGES) { s = esrc_in[e]; d = edst_in[e]; }
  else             { s = d = e - N_EDGES; }          // self-loops
  float nrm = dis[s] * dis[d];
  unsigned pos = atomicAdd(&fill[d], 1u);
  csr[pos] = make_uint2((unsigned)s, __float_as_uint(nrm));
}

// ---------------- dense transform: Y[N][64] = X[N][DIN] @ W[DIN][64] ----------------

template <int DIN>
__global__ __launch_bounds__(256) void k_gemm(const float* __restrict__ X,
                                              const float* __restrict__ W,
                                              float* __restrict__ Y) {
  // 16 rows / block; thread t: col = t&63, rows ty*4..ty*4+3 (ty = t>>6)
  __shared__ float sW[DIN * 64];     // [k][col]
  __shared__ float sXT[DIN][20];     // transposed, padded (+4) to dodge bank conflicts
  const int tid  = threadIdx.x;
  const int col  = tid & 63;
  const int ty   = tid >> 6;         // 0..3
  const int row0 = blockIdx.x * 16;

  for (int i = tid; i < DIN * 64; i += 256) sW[i] = W[i];
  for (int i = tid; i < 16 * DIN; i += 256) {
    int lr = i / DIN, k = i % DIN;
    int r = row0 + lr;
    sXT[k][lr] = (r < N_NODES) ? X[(size_t)r * DIN + k] : 0.f;
  }
  __syncthreads();

  float4 acc = {0.f, 0.f, 0.f, 0.f};
#pragma unroll 4
  for (int k = 0; k < DIN; k++) {
    float w = sW[k * 64 + col];                                  // 2-way (free)
    float4 xv = *reinterpret_cast<const float4*>(&sXT[k][ty * 4]);  // broadcast in-wave
    acc.x += xv.x * w; acc.y += xv.y * w; acc.z += xv.z * w; acc.w += xv.w * w;
  }
#pragma unroll
  for (int r = 0; r < 4; r++) {
    int row = row0 + ty * 4 + r;
    if (row < N_NODES) Y[(size_t)row * 64 + col] = (&acc.x)[r];
  }
}

// ---------------- aggregate: OUT[i][:] = relu?( sum_e nrm*XW[src][:] + b ) ----------------
// Wave-per-node; 8 edges in flight per iteration via float4 gathers.
// lane = grp(=lane>>4, edge slot 0..3) x sub(=lane&15, dim group of 4).

template <bool RELU>
__global__ __launch_bounds__(256) void k_agg(const float4* __restrict__ XW4,
                                             const unsigned* __restrict__ rowptr,
                                             const uint2* __restrict__ csr,
                                             const float4* __restrict__ bias4,
                                             float4* __restrict__ OUT4) {
  int node = (int)((blockIdx.x * blockDim.x + threadIdx.x) >> 6);
  int lane = threadIdx.x & 63;
  if (node >= N_NODES) return;
  const int sub = lane & 15;
  const int grp = lane >> 4;

  unsigned beg = rowptr[node], end = rowptr[node + 1];
  float4 acc0 = {0.f, 0.f, 0.f, 0.f};
  float4 acc1 = {0.f, 0.f, 0.f, 0.f};

  for (unsigned j = beg; j < end; j += 64) {
    int nj = (int)min(64u, end - j);
    unsigned s = 0u; float nrm = 0.f;
    if (lane < nj) {
      uint2 m = csr[j + lane];
      s = m.x; nrm = __uint_as_float(m.y);
    }
    for (int k = 0; k < nj; k += 8) {
      int e0 = k + grp, e1 = k + grp + 4;
      unsigned s0 = (unsigned)__shfl((int)s, e0);
      float    n0 = __shfl(nrm, e0);
      unsigned s1 = (unsigned)__shfl((int)s, e1);
      float    n1 = __shfl(nrm, e1);
      float4 v0 = XW4[(size_t)s0 * 16 + sub];   // 16B/lane, 4 rows per instr
      float4 v1 = XW4[(size_t)s1 * 16 + sub];
      acc0.x += n0 * v0.x; acc0.y += n0 * v0.y; acc0.z += n0 * v0.z; acc0.w += n0 * v0.w;
      acc1.x += n1 * v1.x; acc1.y += n1 * v1.y; acc1.z += n1 * v1.z; acc1.w += n1 * v1.w;
    }
  }

  float4 acc;
  acc.x = acc0.x + acc1.x; acc.y = acc0.y + acc1.y;
  acc.z = acc0.z + acc1.z; acc.w = acc0.w + acc1.w;
  // fold edge-slot partials: grp lives in lane bits 4,5
  acc.x += __shfl_xor(acc.x, 16); acc.y += __shfl_xor(acc.y, 16);
  acc.z += __shfl_xor(acc.z, 16); acc.w += __shfl_xor(acc.w, 16);
  acc.x += __shfl_xor(acc.x, 32); acc.y += __shfl_xor(acc.y, 32);
  acc.z += __shfl_xor(acc.z, 32); acc.w += __shfl_xor(acc.w, 32);

  if (grp == 0) {
    float4 b = bias4[sub];
    acc.x += b.x; acc.y += b.y; acc.z += b.z; acc.w += b.w;
    if (RELU) {
      acc.x = fmaxf(acc.x, 0.f); acc.y = fmaxf(acc.y, 0.f);
      acc.z = fmaxf(acc.z, 0.f); acc.w = fmaxf(acc.w, 0.f);
    }
    OUT4[(size_t)node * 16 + sub] = acc;
  }
}

// ---------------- launch ----------------

extern "C" void kernel_launch(void* const* d_in, const int* in_sizes, int n_in,
                              void* d_out, int out_size, void* d_ws, size_t ws_size,
                              hipStream_t stream) {
  const float* x    = (const float*)d_in[0];
  const int*   eidx = (const int*)d_in[1];      // [2][800000], int32
  const float* W1   = (const float*)d_in[2];
  const float* b1   = (const float*)d_in[3];
  const float* W2   = (const float*)d_in[4];
  const float* b2   = (const float*)d_in[5];
  const float* W3   = (const float*)d_in[6];
  const float* b3   = (const float*)d_in[7];
  float* out = (float*)d_out;

  const int* e_src = eidx;
  const int* e_dst = eidx + N_EDGES;

  size_t off = 0;
  auto alloc = [&](size_t bytes) -> void* {
    void* p = (char*)d_ws + off;
    off += (bytes + 255) & ~(size_t)255;
    return p;
  };
  unsigned* cnt     = (unsigned*)alloc((size_t)N_NODES * 4);
  unsigned* rowptr  = (unsigned*)alloc((size_t)(N_NODES + 1) * 4);
  unsigned* fill    = (unsigned*)alloc((size_t)N_NODES * 4);
  unsigned* bsum    = (unsigned*)alloc((size_t)SCAN_B * 4);
  float*    dis     = (float*)alloc((size_t)N_NODES * 4);
  uint2*    csr     = (uint2*)alloc((size_t)E_TOT * 8);
  float*    xw      = (float*)alloc((size_t)N_NODES * 64 * 4);
  float*    h       = (float*)alloc((size_t)N_NODES * 64 * 4);

  // ---- build graph structure (per call; deterministic work) ----
  hipMemsetAsync(cnt, 0, (size_t)N_NODES * 4, stream);
  k_count<<<(N_EDGES + 255) / 256, 256, 0, stream>>>(e_dst, cnt);
  k_dis<<<(N_NODES + 255) / 256, 256, 0, stream>>>(cnt, dis);
  k_scan1<<<N_SCAN_BLOCKS, SCAN_B, 0, stream>>>(cnt, rowptr, bsum);
  k_scan2<<<1, SCAN_B, 0, stream>>>(bsum);
  k_scan3<<<(N_NODES + 255) / 256, 256, 0, stream>>>(rowptr, fill, bsum);
  k_fill<<<(E_TOT + 255) / 256, 256, 0, stream>>>(e_src, e_dst, dis, fill, csr);

  const int gemm_grid = (N_NODES + 15) / 16;          // 3125
  const int agg_grid  = (N_NODES * 64 + 255) / 256;   // 12500

  // ---- layer 1: 128 -> 64, relu ----
  k_gemm<D_IN><<<gemm_grid, 256, 0, stream>>>(x, W1, xw);
  k_agg<true><<<agg_grid, 256, 0, stream>>>((const float4*)xw, rowptr, csr,
                                            (const float4*)b1, (float4*)h);
  // ---- layer 2: 64 -> 64, relu ----
  k_gemm<D_HID><<<gemm_grid, 256, 0, stream>>>(h, W2, xw);
  k_agg<true><<<agg_grid, 256, 0, stream>>>((const float4*)xw, rowptr, csr,
                                            (const float4*)b2, (float4*)h);
  // ---- layer 3: 64 -> 64, no activation ----
  k_gemm<D_HID><<<gemm_grid, 256, 0, stream>>>(h, W3, xw);
  k_agg<false><<<agg_grid, 256, 0, stream>>>((const float4*)xw, rowptr, csr,
                                             (const float4*)b3, (float4*)out);
}